// Round 12
// baseline (146.663 us; speedup 1.0000x reference)
//
#include <hip/hip_runtime.h>
#include <hip/hip_fp8.h>
#include <stdint.h>
#include <stddef.h>

#define BATCH 8192
#define DIM   256

#define LN2F 0.6931471805599453f
// operand quantization scales; product = 1000*log2(e) = 1442.6950408889634
// so MFMA accs are directly exp2-domain scores (no dequant in hot loop).
#define SCALE_ZJ 16.0f                 // A side (staged)
#define SCALE_ZI 90.16844005556021f    // B side (regs)

typedef int   v4i   __attribute__((ext_vector_type(4)));   // 16B (4 VGPR)
typedef int   v8i   __attribute__((ext_vector_type(8)));   // 32B fp8 frag (8 VGPR)
typedef float f32x4 __attribute__((ext_vector_type(4)));   // 16x16 MFMA acc

// Slot-tiled layout for the 16x16x128 fragment (tile = 16 rows x 256B = 4KB):
//   elem(row, kb) -> (row>>4)*4096 + (kb>>7)*2048 + ((kb>>4)&1)*1024
//                    + (((kb>>5)&3)*16 + (row&15))*16 + (kb&15)
// A-fragment of kstep s: lane reads 16B at s*2048 + lane*16 and +1024 —
// conflict-free ds_read_b128, identity global->LDS staging, coalesced
// B-side global loads. Both sides mirrored -> k-permutation cancels.

// ---------- helpers ----------
static __device__ __forceinline__ uint8_t f2fp8(float f) {
  __hip_fp8_e4m3 q(f);                       // OCP e4m3fn, RNE+sat
  return *reinterpret_cast<uint8_t*>(&q);
}

static __device__ __forceinline__ v8i cat8(v4i lo, v4i hi) {
  return __builtin_shufflevector(lo, hi, 0, 1, 2, 3, 4, 5, 6, 7);
}

// ---------- pass 1: normalize, exact fp32 positives, tiled fp8 store -------
__global__ __launch_bounds__(256) void prep_kernel(
    const float* __restrict__ p1, const float* __restrict__ p2,
    uint8_t* __restrict__ Zi8, uint8_t* __restrict__ Zj8,
    float* __restrict__ pos) {
  const int lane = threadIdx.x & 63;
  const int w    = threadIdx.x >> 6;
  const int row  = blockIdx.x * 4 + w;   // one wave per row

  const float4 x1 = ((const float4*)p1)[row * 64 + lane];
  const float4 x2 = ((const float4*)p2)[row * 64 + lane];
  float ss1 = x1.x * x1.x + x1.y * x1.y + x1.z * x1.z + x1.w * x1.w;
  float ss2 = x2.x * x2.x + x2.y * x2.y + x2.z * x2.z + x2.w * x2.w;
  float d   = x1.x * x2.x + x1.y * x2.y + x1.z * x2.z + x1.w * x2.w;
#pragma unroll
  for (int m = 1; m < 64; m <<= 1) {
    ss1 += __shfl_xor(ss1, m);
    ss2 += __shfl_xor(ss2, m);
    d   += __shfl_xor(d, m);
  }
  const float n1 = fmaxf(sqrtf(ss1), 1e-12f);
  const float n2 = fmaxf(sqrtf(ss2), 1e-12f);
  if (lane == 0) pos[row] = d / (n1 * n2);          // exact fp32 diagonal

  const float sI = SCALE_ZI / n1;
  const float sJ = SCALE_ZJ / n2;
  uchar4 u1, u2;
  u1.x = f2fp8(x1.x * sI); u1.y = f2fp8(x1.y * sI);
  u1.z = f2fp8(x1.z * sI); u1.w = f2fp8(x1.w * sI);
  u2.x = f2fp8(x2.x * sJ); u2.y = f2fp8(x2.y * sJ);
  u2.z = f2fp8(x2.z * sJ); u2.w = f2fp8(x2.w * sJ);

  // lane holds kb = 4*lane .. 4*lane+3 -> tiled address (see layout comment)
  const size_t tb = (size_t)(row >> 4) * 4096;
  const int off = (lane >> 5) * 2048 + ((lane >> 2) & 1) * 1024 +
                  (((lane >> 3) & 3) * 16 + (row & 15)) * 16 + (lane & 3) * 4;
  *(uchar4*)(Zi8 + tb + off) = u1;
  *(uchar4*)(Zj8 + tb + off) = u2;
}

// ---------- online lse update for one 4-score acc block ----------
static __device__ __forceinline__ void lse_update4(const f32x4& a,
                                                   float& m, float& l) {
  const float tmax = fmaxf(fmaxf(a[0], a[1]), fmaxf(a[2], a[3]));
  const float mn = fmaxf(m, tmax);
  const float sum = (__builtin_amdgcn_exp2f(a[0] - mn) +
                     __builtin_amdgcn_exp2f(a[1] - mn)) +
                    (__builtin_amdgcn_exp2f(a[2] - mn) +
                     __builtin_amdgcn_exp2f(a[3] - mn));
  l = l * __builtin_amdgcn_exp2f(m - mn) + sum;
  m = mn;
}

// ---------- pass 2: fused fp8 MFMA GEMM + online logsumexp ----------
// acc = mfma_scale_16x16x128(A=Zj_frag, B=Zi_frag, unit scales) -> D[j][i]:
// i = lane&15, j = (lane>>4)*4 + reg. Wave owns 4 i-tiles (64 i); each av
// (2 conflict-free b128) feeds 4 MFMAs; 4 independent acc chains of 4 regs.
// grid = 32 row-blocks (256 i) x 64 j-chunks (128 cols = 32KB LDS).
// ~118 VGPR fits (256,4)=128 cap -> 4 blocks/CU x 4 waves = 16 waves/CU in
// INDEPENDENT blocks that drift into different (stage/MFMA/softmax) phases —
// the cross-pipe overlap lockstep big-block rounds lacked (R2-R11 plateau:
// time ~ sum of pipe times, not max). One barrier per block total.
__global__ __launch_bounds__(256, 4) void lse_kernel(
    const uint8_t* __restrict__ Zi8, const uint8_t* __restrict__ Zj8,
    float* __restrict__ plse) {
  const int bid   = blockIdx.x;
  const int chunk = bid & 63;
  const int rb    = bid >> 6;
  const int tid   = threadIdx.x;
  const int lane  = tid & 63;
  const int r16   = lane & 15;
  const int w     = tid >> 6;
  const int iBase = rb * 256 + w * 64;

  __shared__ __align__(16) uint8_t lds[32768];  // 8 j-tiles of 16 cols

  const uint8_t* src = Zj8 + (size_t)chunk * 32768;
  // stage whole chunk: identity mapping (uniform base, HW adds lane*16)
#pragma unroll
  for (int it = 0; it < 8; ++it) {
    const int off = it * 4096 + tid * 16;
    __builtin_amdgcn_global_load_lds(
        (const __attribute__((address_space(1))) void*)(src + off),
        (__attribute__((address_space(3))) void*)(lds + off), 16, 0, 0);
  }

  // B fragments: 4 i-tiles x 2 ksteps, coalesced tiled loads (64 VGPR).
  v8i b[4][2];
  const uint8_t* zb = Zi8 + (size_t)(rb * 16 + w * 4) * 4096 + lane * 16;
#pragma unroll
  for (int it = 0; it < 4; ++it) {
#pragma unroll
    for (int s = 0; s < 2; ++s) {
      const uint8_t* base = zb + it * 4096 + s * 2048;
      b[it][s] = cat8(*(const v4i*)(base), *(const v4i*)(base + 1024));
    }
  }
#pragma unroll
  for (int it = 0; it < 4; ++it) {
    asm("" : "+v"(b[it][0]));
    asm("" : "+v"(b[it][1]));
  }

  float m[4], l[4];
#pragma unroll
  for (int it = 0; it < 4; ++it) { m[it] = -1e30f; l[it] = 0.f; }

  __syncthreads();  // single barrier: whole chunk + b-frags resident

#pragma unroll
  for (int t = 0; t < 8; ++t) {
    const uint8_t* buf = lds + t * 4096 + lane * 16;
    f32x4 acc0 = {}, acc1 = {}, acc2 = {}, acc3 = {};
    __builtin_amdgcn_s_setprio(1);
#pragma unroll
    for (int s = 0; s < 2; ++s) {
      const v8i av = cat8(*(const v4i*)(buf + s * 2048),
                          *(const v4i*)(buf + s * 2048 + 1024));
      acc0 = __builtin_amdgcn_mfma_scale_f32_16x16x128_f8f6f4(
          av, b[0][s], acc0, 0, 0, 0, 0x7F7F7F7F, 0, 0x7F7F7F7F);
      acc1 = __builtin_amdgcn_mfma_scale_f32_16x16x128_f8f6f4(
          av, b[1][s], acc1, 0, 0, 0, 0x7F7F7F7F, 0, 0x7F7F7F7F);
      acc2 = __builtin_amdgcn_mfma_scale_f32_16x16x128_f8f6f4(
          av, b[2][s], acc2, 0, 0, 0, 0x7F7F7F7F, 0, 0x7F7F7F7F);
      acc3 = __builtin_amdgcn_mfma_scale_f32_16x16x128_f8f6f4(
          av, b[3][s], acc3, 0, 0, 0, 0x7F7F7F7F, 0, 0x7F7F7F7F);
    }
    __builtin_amdgcn_s_setprio(0);
    lse_update4(acc0, m[0], l[0]);
    lse_update4(acc1, m[1], l[1]);
    lse_update4(acc2, m[2], l[2]);
    lse_update4(acc3, m[3], l[3]);
  }

  // combine the 4 lane-groups (each holds a different j-quarter of the tile)
#pragma unroll
  for (int it = 0; it < 4; ++it) {
    float mm = m[it], ll = l[it];
#pragma unroll
    for (int msk = 16; msk < 64; msk <<= 1) {
      const float mo = __shfl_xor(mm, msk);
      const float lo = __shfl_xor(ll, msk);
      const float mn = fmaxf(mm, mo);
      ll = ll * __builtin_amdgcn_exp2f(mm - mn) +
           lo * __builtin_amdgcn_exp2f(mo - mn);
      mm = mn;
    }
    if (lane < 16) {
      const int i = iBase + it * 16 + r16;
      // log2-domain partial lse, [i][chunk] for vectorized finalize reads
      plse[(size_t)i * 64 + chunk] = mm + __builtin_amdgcn_logf(ll);
    }
  }
}

// ---------- pass 3: per-row combine + grid reduction (last-block ticket) ---
__global__ __launch_bounds__(256) void finalize_kernel(
    const float* __restrict__ plse, const float* __restrict__ pos,
    float2* __restrict__ bpart, unsigned int* __restrict__ counter,
    float* __restrict__ out) {
  const int tid = threadIdx.x;
  const int row = blockIdx.x * 256 + tid;
  float v[64];
#pragma unroll
  for (int c = 0; c < 16; ++c) {
    const float4 q = ((const float4*)(plse + (size_t)row * 64))[c];
    v[c * 4 + 0] = q.x; v[c * 4 + 1] = q.y; v[c * 4 + 2] = q.z; v[c * 4 + 3] = q.w;
  }
  float M = v[0];
#pragma unroll
  for (int c = 1; c < 64; ++c) M = fmaxf(M, v[c]);
  float S = 0.0f;
#pragma unroll
  for (int c = 0; c < 64; ++c) S += __builtin_amdgcn_exp2f(v[c] - M);
  const float lse = LN2F * (M + __builtin_amdgcn_logf(S));  // natural-log lse
  const float pv  = pos[row];
  float lsum = lse - 1000.0f * pv;
  float psum = pv;
#pragma unroll
  for (int msk = 1; msk < 64; msk <<= 1) {
    lsum += __shfl_xor(lsum, msk);
    psum += __shfl_xor(psum, msk);
  }
  __shared__ float sl[4], sp[4];
  const int w = tid >> 6, lane = tid & 63;
  if (lane == 0) { sl[w] = lsum; sp[w] = psum; }
  __syncthreads();
  if (tid == 0) {
    union { float2 f; unsigned long long u; } pk;
    pk.f = make_float2(sl[0] + sl[1] + sl[2] + sl[3],
                       sp[0] + sp[1] + sp[2] + sp[3]);
    __hip_atomic_store((unsigned long long*)&bpart[blockIdx.x], pk.u,
                       __ATOMIC_RELEASE, __HIP_MEMORY_SCOPE_AGENT);
    const unsigned int t = __hip_atomic_fetch_add(
        counter, 1u, __ATOMIC_ACQ_REL, __HIP_MEMORY_SCOPE_AGENT);
    if (t == 31u) {  // last block: deterministic ordered reduce of 32 partials
      float L = 0.f, P = 0.f;
#pragma unroll
      for (int i = 0; i < 32; ++i) {
        union { float2 f; unsigned long long u; } q2;
        q2.u = __hip_atomic_load((const unsigned long long*)&bpart[i],
                                 __ATOMIC_ACQUIRE, __HIP_MEMORY_SCOPE_AGENT);
        L += q2.f.x; P += q2.f.y;
      }
      out[0] = L / (float)BATCH;  // loss
      out[1] = P;                 // sum(positives)
    }
  }
}

extern "C" void kernel_launch(void* const* d_in, const int* in_sizes, int n_in,
                              void* d_out, int out_size, void* d_ws, size_t ws_size,
                              hipStream_t stream) {
  const float* p1 = (const float*)d_in[0];
  const float* p2 = (const float*)d_in[1];
  float* out = (float*)d_out;
  uint8_t* ws = (uint8_t*)d_ws;

  uint8_t* Zi8          = ws;                                                  // 2 MB (tiled)
  uint8_t* Zj8          = ws + (size_t)2 * 1024 * 1024;                        // 2 MB (tiled)
  float* pos            = (float*)(ws + (size_t)4 * 1024 * 1024);              // 32 KB
  float2* bpart         = (float2*)(ws + (size_t)4 * 1024 * 1024 + 32 * 1024); // 256 B
  unsigned int* counter = (unsigned int*)(ws + (size_t)4 * 1024 * 1024 + 40 * 1024); // 4 B
  float* plse           = (float*)(ws + (size_t)4 * 1024 * 1024 + 64 * 1024);  // 2 MB

  hipMemsetAsync(counter, 0, sizeof(unsigned int), stream);
  prep_kernel<<<dim3(2048), dim3(256), 0, stream>>>(p1, p2, Zi8, Zj8, pos);
  lse_kernel<<<dim3(2048), dim3(256), 0, stream>>>(Zi8, Zj8, plse);
  finalize_kernel<<<dim3(32), dim3(256), 0, stream>>>(plse, pos, bpart, counter, out);
}

// Round 13
// 96.399 us; speedup vs baseline: 1.5214x; 1.5214x over previous
//
#include <hip/hip_runtime.h>
#include <hip/hip_fp8.h>
#include <stdint.h>
#include <stddef.h>

#define BATCH 8192
#define DIM   256

#define LN2F 0.6931471805599453f
// operand quantization scales; product = 1000*log2(e) = 1442.6950408889634
// so MFMA accs are directly exp2-domain scores (no dequant in hot loop).
#define SCALE_ZJ 16.0f                 // A side (staged)
#define SCALE_ZI 90.16844005556021f    // B side (regs)

typedef int   v4i   __attribute__((ext_vector_type(4)));   // 16B (4 VGPR)
typedef int   v8i   __attribute__((ext_vector_type(8)));   // 32B fp8 frag (8 VGPR)
typedef float f32x4 __attribute__((ext_vector_type(4)));   // 16x16 MFMA acc

// Slot-tiled layout for the 16x16x128 fragment (tile = 16 rows x 256B = 4KB):
//   elem(row, kb) -> (row>>4)*4096 + (kb>>7)*2048 + ((kb>>4)&1)*1024
//                    + (((kb>>5)&3)*16 + (row&15))*16 + (kb&15)
// A-fragment of kstep s: lane reads 16B at s*2048 + lane*16 and +1024 —
// conflict-free ds_read_b128, identity global->LDS staging, coalesced
// B-side global loads. Both sides mirrored -> k-permutation cancels.
//
// LAUNCH-BOUND RULE (R5/R7/R12, 3 strikes): min_waves=4 makes the allocator
// clamp to the 64-VGPR step and spill accumulators to scratch (100-300MB of
// FETCH/WRITE, MfmaUtil ~5%). ONLY (256,3)/(256,2)/default are safe. Actual
// demand here is ~120 VGPR, so with the 168 cap the HW occupancy still
// reaches 4 blocks/CU if the allocator lands <=128.

// ---------- helpers ----------
static __device__ __forceinline__ uint8_t f2fp8(float f) {
  __hip_fp8_e4m3 q(f);                       // OCP e4m3fn, RNE+sat
  return *reinterpret_cast<uint8_t*>(&q);
}

static __device__ __forceinline__ v8i cat8(v4i lo, v4i hi) {
  return __builtin_shufflevector(lo, hi, 0, 1, 2, 3, 4, 5, 6, 7);
}

// ---------- pass 1: normalize, exact fp32 positives, tiled fp8 store -------
__global__ __launch_bounds__(256) void prep_kernel(
    const float* __restrict__ p1, const float* __restrict__ p2,
    uint8_t* __restrict__ Zi8, uint8_t* __restrict__ Zj8,
    float* __restrict__ pos) {
  const int lane = threadIdx.x & 63;
  const int w    = threadIdx.x >> 6;
  const int row  = blockIdx.x * 4 + w;   // one wave per row

  const float4 x1 = ((const float4*)p1)[row * 64 + lane];
  const float4 x2 = ((const float4*)p2)[row * 64 + lane];
  float ss1 = x1.x * x1.x + x1.y * x1.y + x1.z * x1.z + x1.w * x1.w;
  float ss2 = x2.x * x2.x + x2.y * x2.y + x2.z * x2.z + x2.w * x2.w;
  float d   = x1.x * x2.x + x1.y * x2.y + x1.z * x2.z + x1.w * x2.w;
#pragma unroll
  for (int m = 1; m < 64; m <<= 1) {
    ss1 += __shfl_xor(ss1, m);
    ss2 += __shfl_xor(ss2, m);
    d   += __shfl_xor(d, m);
  }
  const float n1 = fmaxf(sqrtf(ss1), 1e-12f);
  const float n2 = fmaxf(sqrtf(ss2), 1e-12f);
  if (lane == 0) pos[row] = d / (n1 * n2);          // exact fp32 diagonal

  const float sI = SCALE_ZI / n1;
  const float sJ = SCALE_ZJ / n2;
  uchar4 u1, u2;
  u1.x = f2fp8(x1.x * sI); u1.y = f2fp8(x1.y * sI);
  u1.z = f2fp8(x1.z * sI); u1.w = f2fp8(x1.w * sI);
  u2.x = f2fp8(x2.x * sJ); u2.y = f2fp8(x2.y * sJ);
  u2.z = f2fp8(x2.z * sJ); u2.w = f2fp8(x2.w * sJ);

  // lane holds kb = 4*lane .. 4*lane+3 -> tiled address (see layout comment)
  const size_t tb = (size_t)(row >> 4) * 4096;
  const int off = (lane >> 5) * 2048 + ((lane >> 2) & 1) * 1024 +
                  (((lane >> 3) & 3) * 16 + (row & 15)) * 16 + (lane & 3) * 4;
  *(uchar4*)(Zi8 + tb + off) = u1;
  *(uchar4*)(Zj8 + tb + off) = u2;
}

// ---------- online lse update for one 4-score acc block ----------
static __device__ __forceinline__ void lse_update4(const f32x4& a,
                                                   float& m, float& l) {
  const float tmax = fmaxf(fmaxf(a[0], a[1]), fmaxf(a[2], a[3]));
  const float mn = fmaxf(m, tmax);
  const float sum = (__builtin_amdgcn_exp2f(a[0] - mn) +
                     __builtin_amdgcn_exp2f(a[1] - mn)) +
                    (__builtin_amdgcn_exp2f(a[2] - mn) +
                     __builtin_amdgcn_exp2f(a[3] - mn));
  l = l * __builtin_amdgcn_exp2f(m - mn) + sum;
  m = mn;
}

// ---------- pass 2: fused fp8 MFMA GEMM + online logsumexp ----------
// acc = mfma_scale_16x16x128(A=Zj_frag, B=Zi_frag, unit scales) -> D[j][i]:
// i = lane&15, j = (lane>>4)*4 + reg. Wave owns 4 i-tiles (64 i); each av
// (2 conflict-free b128) feeds 4 MFMAs; 4 independent acc chains of 4 regs.
// grid = 32 row-blocks (256 i) x 64 j-chunks (128 cols = 32KB LDS).
// Small independent blocks drift into different (stage/MFMA/softmax) phases
// -> cross-pipe overlap. One barrier per block total.
__global__ __launch_bounds__(256, 3) void lse_kernel(
    const uint8_t* __restrict__ Zi8, const uint8_t* __restrict__ Zj8,
    float* __restrict__ plse) {
  const int bid   = blockIdx.x;
  const int chunk = bid & 63;
  const int rb    = bid >> 6;
  const int tid   = threadIdx.x;
  const int lane  = tid & 63;
  const int r16   = lane & 15;
  const int w     = tid >> 6;
  const int iBase = rb * 256 + w * 64;

  __shared__ __align__(16) uint8_t lds[32768];  // 8 j-tiles of 16 cols

  const uint8_t* src = Zj8 + (size_t)chunk * 32768;
  // stage whole chunk: identity mapping (uniform base, HW adds lane*16)
#pragma unroll
  for (int it = 0; it < 8; ++it) {
    const int off = it * 4096 + tid * 16;
    __builtin_amdgcn_global_load_lds(
        (const __attribute__((address_space(1))) void*)(src + off),
        (__attribute__((address_space(3))) void*)(lds + off), 16, 0, 0);
  }

  // B fragments: 4 i-tiles x 2 ksteps, coalesced tiled loads (64 VGPR).
  v8i b[4][2];
  const uint8_t* zb = Zi8 + (size_t)(rb * 16 + w * 4) * 4096 + lane * 16;
#pragma unroll
  for (int it = 0; it < 4; ++it) {
#pragma unroll
    for (int s = 0; s < 2; ++s) {
      const uint8_t* base = zb + it * 4096 + s * 2048;
      b[it][s] = cat8(*(const v4i*)(base), *(const v4i*)(base + 1024));
    }
  }
#pragma unroll
  for (int it = 0; it < 4; ++it) {
    asm("" : "+v"(b[it][0]));
    asm("" : "+v"(b[it][1]));
  }

  float m[4], l[4];
#pragma unroll
  for (int it = 0; it < 4; ++it) { m[it] = -1e30f; l[it] = 0.f; }

  __syncthreads();  // single barrier: whole chunk + b-frags resident

#pragma unroll
  for (int t = 0; t < 8; ++t) {
    const uint8_t* buf = lds + t * 4096 + lane * 16;
    f32x4 acc0 = {}, acc1 = {}, acc2 = {}, acc3 = {};
    __builtin_amdgcn_s_setprio(1);
#pragma unroll
    for (int s = 0; s < 2; ++s) {
      const v8i av = cat8(*(const v4i*)(buf + s * 2048),
                          *(const v4i*)(buf + s * 2048 + 1024));
      acc0 = __builtin_amdgcn_mfma_scale_f32_16x16x128_f8f6f4(
          av, b[0][s], acc0, 0, 0, 0, 0x7F7F7F7F, 0, 0x7F7F7F7F);
      acc1 = __builtin_amdgcn_mfma_scale_f32_16x16x128_f8f6f4(
          av, b[1][s], acc1, 0, 0, 0, 0x7F7F7F7F, 0, 0x7F7F7F7F);
      acc2 = __builtin_amdgcn_mfma_scale_f32_16x16x128_f8f6f4(
          av, b[2][s], acc2, 0, 0, 0, 0x7F7F7F7F, 0, 0x7F7F7F7F);
      acc3 = __builtin_amdgcn_mfma_scale_f32_16x16x128_f8f6f4(
          av, b[3][s], acc3, 0, 0, 0, 0x7F7F7F7F, 0, 0x7F7F7F7F);
    }
    __builtin_amdgcn_s_setprio(0);
    lse_update4(acc0, m[0], l[0]);
    lse_update4(acc1, m[1], l[1]);
    lse_update4(acc2, m[2], l[2]);
    lse_update4(acc3, m[3], l[3]);
  }

  // combine the 4 lane-groups (each holds a different j-quarter of the tile)
#pragma unroll
  for (int it = 0; it < 4; ++it) {
    float mm = m[it], ll = l[it];
#pragma unroll
    for (int msk = 16; msk < 64; msk <<= 1) {
      const float mo = __shfl_xor(mm, msk);
      const float lo = __shfl_xor(ll, msk);
      const float mn = fmaxf(mm, mo);
      ll = ll * __builtin_amdgcn_exp2f(mm - mn) +
           lo * __builtin_amdgcn_exp2f(mo - mn);
      mm = mn;
    }
    if (lane < 16) {
      const int i = iBase + it * 16 + r16;
      // log2-domain partial lse, [i][chunk] for vectorized finalize reads
      plse[(size_t)i * 64 + chunk] = mm + __builtin_amdgcn_logf(ll);
    }
  }
}

// ---------- pass 3: per-row combine + grid reduction (last-block ticket) ---
__global__ __launch_bounds__(256) void finalize_kernel(
    const float* __restrict__ plse, const float* __restrict__ pos,
    float2* __restrict__ bpart, unsigned int* __restrict__ counter,
    float* __restrict__ out) {
  const int tid = threadIdx.x;
  const int row = blockIdx.x * 256 + tid;
  float v[64];
#pragma unroll
  for (int c = 0; c < 16; ++c) {
    const float4 q = ((const float4*)(plse + (size_t)row * 64))[c];
    v[c * 4 + 0] = q.x; v[c * 4 + 1] = q.y; v[c * 4 + 2] = q.z; v[c * 4 + 3] = q.w;
  }
  float M = v[0];
#pragma unroll
  for (int c = 1; c < 64; ++c) M = fmaxf(M, v[c]);
  float S = 0.0f;
#pragma unroll
  for (int c = 0; c < 64; ++c) S += __builtin_amdgcn_exp2f(v[c] - M);
  const float lse = LN2F * (M + __builtin_amdgcn_logf(S));  // natural-log lse
  const float pv  = pos[row];
  float lsum = lse - 1000.0f * pv;
  float psum = pv;
#pragma unroll
  for (int msk = 1; msk < 64; msk <<= 1) {
    lsum += __shfl_xor(lsum, msk);
    psum += __shfl_xor(psum, msk);
  }
  __shared__ float sl[4], sp[4];
  const int w = tid >> 6, lane = tid & 63;
  if (lane == 0) { sl[w] = lsum; sp[w] = psum; }
  __syncthreads();
  if (tid == 0) {
    union { float2 f; unsigned long long u; } pk;
    pk.f = make_float2(sl[0] + sl[1] + sl[2] + sl[3],
                       sp[0] + sp[1] + sp[2] + sp[3]);
    __hip_atomic_store((unsigned long long*)&bpart[blockIdx.x], pk.u,
                       __ATOMIC_RELEASE, __HIP_MEMORY_SCOPE_AGENT);
    const unsigned int t = __hip_atomic_fetch_add(
        counter, 1u, __ATOMIC_ACQ_REL, __HIP_MEMORY_SCOPE_AGENT);
    if (t == 31u) {  // last block: deterministic ordered reduce of 32 partials
      float L = 0.f, P = 0.f;
#pragma unroll
      for (int i = 0; i < 32; ++i) {
        union { float2 f; unsigned long long u; } q2;
        q2.u = __hip_atomic_load((const unsigned long long*)&bpart[i],
                                 __ATOMIC_ACQUIRE, __HIP_MEMORY_SCOPE_AGENT);
        L += q2.f.x; P += q2.f.y;
      }
      out[0] = L / (float)BATCH;  // loss
      out[1] = P;                 // sum(positives)
    }
  }
}

extern "C" void kernel_launch(void* const* d_in, const int* in_sizes, int n_in,
                              void* d_out, int out_size, void* d_ws, size_t ws_size,
                              hipStream_t stream) {
  const float* p1 = (const float*)d_in[0];
  const float* p2 = (const float*)d_in[1];
  float* out = (float*)d_out;
  uint8_t* ws = (uint8_t*)d_ws;

  uint8_t* Zi8          = ws;                                                  // 2 MB (tiled)
  uint8_t* Zj8          = ws + (size_t)2 * 1024 * 1024;                        // 2 MB (tiled)
  float* pos            = (float*)(ws + (size_t)4 * 1024 * 1024);              // 32 KB
  float2* bpart         = (float2*)(ws + (size_t)4 * 1024 * 1024 + 32 * 1024); // 256 B
  unsigned int* counter = (unsigned int*)(ws + (size_t)4 * 1024 * 1024 + 40 * 1024); // 4 B
  float* plse           = (float*)(ws + (size_t)4 * 1024 * 1024 + 64 * 1024);  // 2 MB

  hipMemsetAsync(counter, 0, sizeof(unsigned int), stream);
  prep_kernel<<<dim3(2048), dim3(256), 0, stream>>>(p1, p2, Zi8, Zj8, pos);
  lse_kernel<<<dim3(2048), dim3(256), 0, stream>>>(Zi8, Zj8, plse);
  finalize_kernel<<<dim3(32), dim3(256), 0, stream>>>(plse, pos, bpart, counter, out);
}